// Round 3
// baseline (146.413 us; speedup 1.0000x reference)
//
#include <hip/hip_runtime.h>
#include <hip/hip_bf16.h>

#define DI __device__ __forceinline__

using f32x4  = __attribute__((ext_vector_type(4)))  float;
using f32x16 = __attribute__((ext_vector_type(16))) float;
using s16x8  = __attribute__((ext_vector_type(8)))  short;
using s32x4  = __attribute__((ext_vector_type(4)))  int;
using u16x4  = __attribute__((ext_vector_type(4)))  unsigned short;
using u32x4  = __attribute__((ext_vector_type(4)))  unsigned;

#if __has_builtin(__builtin_amdgcn_global_load_lds)
#define HAS_GLDS 1
#else
#define HAS_GLDS 0
#endif

typedef __attribute__((address_space(3))) unsigned       lds_u32;
typedef const __attribute__((address_space(1))) unsigned ga_u32;

DI unsigned short f2bf(float f) {
  union { float f; unsigned u; } v; v.f = f;
  unsigned r = v.u + 0x7FFFu + ((v.u >> 16) & 1u);   // RNE
  return (unsigned short)(r >> 16);
}

DI unsigned cvtpk(float lo, float hi) {
  unsigned d;
  asm("v_cvt_pk_bf16_f32 %0, %1, %2" : "=v"(d) : "v"(lo), "v"(hi));
  return d;
}
DI void pswap(unsigned &a, unsigned &b) {
  asm("v_permlane32_swap_b32 %0, %1" : "+v"(a), "+v"(b));
}

// Q scale: 1/sqrt(64) * log2(e)  (scores land in log2 domain -> exp2 in attn)
#define QSCALE 0.18033688011112042f

// ---------------- fused prep: x->bf16, W_{Q,K,V}->Wt[w][n][h][k], W_O->Wot[d][k] ----------------
__global__ void k_prep(const float* __restrict__ x, const float* __restrict__ wq,
                       const float* __restrict__ wk, const float* __restrict__ wv,
                       const float* __restrict__ wo, unsigned short* __restrict__ xb,
                       unsigned short* __restrict__ Wt, unsigned short* __restrict__ Wot) {
  int bid = blockIdx.x;
  if (bid < 4096) {                                  // x convert, vec4
    int i = (bid * 256 + threadIdx.x) * 4;
    f32x4 v = *reinterpret_cast<const f32x4*>(x + i);
    u16x4 o;
    o[0] = f2bf(v[0]); o[1] = f2bf(v[1]); o[2] = f2bf(v[2]); o[3] = f2bf(v[3]);
    *reinterpret_cast<u16x4*>(xb + i) = o;
  } else if (bid < 16384) {                          // Wt (transpose h<->k)
    int o = (bid - 4096) * 256 + threadIdx.x;        // 3*16*64*1024
    int k = o & 1023, h = (o >> 10) & 63, n = (o >> 16) & 15, w = o >> 20;
    const float* W = (w == 0) ? wq : (w == 1) ? wk : wv;
    Wt[o] = f2bf(W[(n * 1024 + k) * 64 + h]);
  } else {                                           // Wot (plain transpose)
    int o = (bid - 16384) * 256 + threadIdx.x;       // 1024*1024
    int k = o & 1023, d = o >> 10;
    Wot[o] = f2bf(wo[k * 1024 + d]);
  }
}

// ---------------- GEMM: C[M,c] = A[M,K] * Bt[c,K]^T ----------------
// MODE 0: QKV proj (bias; QSCALE on Q; Q,K -> [b][n][p][h]; V -> [b][n][h][p])
// MODE 1: output proj (bias b_O, fp32 out [m][c])
template <int MODE>
__launch_bounds__(256, 2)
__global__ void k_gemm(const unsigned short* __restrict__ A,
                       const unsigned short* __restrict__ Bt,
                       const float* __restrict__ bq, const float* __restrict__ bk,
                       const float* __restrict__ bv, const float* __restrict__ bo,
                       unsigned short* __restrict__ oq, unsigned short* __restrict__ ok_,
                       unsigned short* __restrict__ ov, float* __restrict__ of) {
  __shared__ __align__(16) unsigned short As[128 * 64];
  __shared__ __align__(16) unsigned short Bs[128 * 64];
  const int t = threadIdx.x;
  const int lane = t & 63, wid = t >> 6;
  const int wm = wid >> 1, wn = wid & 1;
  const int l15 = lane & 15, l4 = lane >> 4;
  const int m0 = blockIdx.y * 128, c0 = blockIdx.x * 128;

  f32x4 acc[4][4] = {};

  for (int k0 = 0; k0 < 1024; k0 += 64) {
    if (k0) __syncthreads();
#if HAS_GLDS
    {
      const int r_l = lane >> 3, kb = lane & 7;
#pragma unroll
      for (int i = 0; i < 4; ++i) {
        int r = wid * 32 + i * 8 + r_l;
        int ksrc = (kb ^ (r & 7)) * 8;               // pre-swizzled global source (rule #21)
        __builtin_amdgcn_global_load_lds(
            (ga_u32*)(A + (long)(m0 + r) * 1024 + k0 + ksrc),
            (lds_u32*)((__attribute__((address_space(3))) unsigned short*)As + (wid * 32 + i * 8) * 64),
            16, 0, 0);
        __builtin_amdgcn_global_load_lds(
            (ga_u32*)(Bt + (long)(c0 + r) * 1024 + k0 + ksrc),
            (lds_u32*)((__attribute__((address_space(3))) unsigned short*)Bs + (wid * 32 + i * 8) * 64),
            16, 0, 0);
      }
    }
#else
#pragma unroll
    for (int i = 0; i < 4; ++i) {
      int idx = i * 256 + t;
      int r = idx >> 3, kb = idx & 7;
      int lo = r * 64 + (((kb * 16) ^ ((r & 7) << 4)) >> 1);
      *reinterpret_cast<s16x8*>(&As[lo]) =
          *reinterpret_cast<const s16x8*>(A + (m0 + r) * 1024 + k0 + kb * 8);
      *reinterpret_cast<s16x8*>(&Bs[lo]) =
          *reinterpret_cast<const s16x8*>(Bt + (c0 + r) * 1024 + k0 + kb * 8);
    }
#endif
    __syncthreads();
    s16x8 af[4][2], bf[4][2];
#pragma unroll
    for (int mb = 0; mb < 4; ++mb) {
      int r = wm * 64 + mb * 16 + l15;
#pragma unroll
      for (int kc = 0; kc < 2; ++kc) {
        int byo = (kc * 64 + l4 * 16) ^ ((r & 7) << 4);
        af[mb][kc] = *reinterpret_cast<const s16x8*>(&As[r * 64 + (byo >> 1)]);
      }
    }
#pragma unroll
    for (int nb = 0; nb < 4; ++nb) {
      int r = wn * 64 + nb * 16 + l15;
#pragma unroll
      for (int kc = 0; kc < 2; ++kc) {
        int byo = (kc * 64 + l4 * 16) ^ ((r & 7) << 4);
        bf[nb][kc] = *reinterpret_cast<const s16x8*>(&Bs[r * 64 + (byo >> 1)]);
      }
    }
#pragma unroll
    for (int mb = 0; mb < 4; ++mb)
#pragma unroll
      for (int nb = 0; nb < 4; ++nb) {
        acc[mb][nb] = __builtin_amdgcn_mfma_f32_16x16x32_bf16(af[mb][0], bf[nb][0], acc[mb][nb], 0, 0, 0);
        acc[mb][nb] = __builtin_amdgcn_mfma_f32_16x16x32_bf16(af[mb][1], bf[nb][1], acc[mb][nb], 0, 0, 0);
      }
  }

#pragma unroll
  for (int mb = 0; mb < 4; ++mb) {
#pragma unroll
    for (int nb = 0; nb < 4; ++nb) {
      int c = c0 + wn * 64 + nb * 16 + l15;
      int mbase = m0 + wm * 64 + mb * 16 + l4 * 4;
      if (MODE == 0) {
        int w = c >> 10, cc = c & 1023;
        int nH = cc >> 6, h = cc & 63;
        const float* bias = (w == 0) ? bq : (w == 1) ? bk : bv;
        float bval = bias[cc];
        if (w == 2) {                       // V -> transposed [b][n][h][p]
          int bb = mbase >> 11, p = mbase & 2047;
          u16x4 pk4;
#pragma unroll
          for (int r = 0; r < 4; ++r) pk4[r] = f2bf(acc[mb][nb][r] + bval);
          *reinterpret_cast<u16x4*>(ov + (((long)bb * 16 + nH) * 64 + h) * 2048 + p) = pk4;
        } else {
          unsigned short* dst = (w == 0) ? oq : ok_;
          float scl = (w == 0) ? QSCALE : 1.0f;
#pragma unroll
          for (int r = 0; r < 4; ++r) {
            int m = mbase + r;
            int bb = m >> 11, p = m & 2047;
            dst[(((long)bb * 16 + nH) * 2048 + p) * 64 + h] = f2bf((acc[mb][nb][r] + bval) * scl);
          }
        }
      } else {
#pragma unroll
        for (int r = 0; r < 4; ++r) of[(long)(mbase + r) * 1024 + c] = acc[mb][nb][r] + bo[c];
      }
    }
  }
}

// ---------------- flash attention (causal), barrier-free, mirror-balanced ----------------
// 512 blocks x 2 waves; wave owns 32 q-rows of tile g, then of tile 63-g (work = 33 k-tiles const)
__launch_bounds__(128, 2)
__global__ void k_attn(const unsigned short* __restrict__ Q,
                       const unsigned short* __restrict__ K,
                       const unsigned short* __restrict__ VT,
                       unsigned short* __restrict__ Z) {
  __shared__ unsigned Zl[2][32 * 33];
  const int t = threadIdx.x;
  const int lane = t & 63, wv = t >> 6;
  const int l31 = lane & 31, h5 = lane >> 5;
  const int id = blockIdx.x;                    // 512
  const int bn = (id & 7) + 8 * (id >> 7);      // XCD(id%8) groups same-bn blocks
  const int pp = (id >> 3) & 15;
  const int g0 = pp * 2 + wv;                   // [0,32)
  const int b = bn >> 4, n = bn & 15;
  const unsigned short* Qb = Q + (long)bn * (2048 * 64);
  const unsigned short* Kb = K + (long)bn * (2048 * 64);
  const unsigned short* Vb = VT + (long)bn * (64 * 2048);
  unsigned* Zd = (unsigned*)Z;

  for (int ph = 0; ph < 2; ++ph) {
    const int g = ph ? 63 - g0 : g0;            // mirrored pair: total work const
    const int r0 = g * 32;
    const int qq = r0 + l31;
    const int qmax = r0 + 31;

    s16x8 qf[4];
#pragma unroll
    for (int hc = 0; hc < 4; ++hc)
      qf[hc] = *reinterpret_cast<const s16x8*>(Qb + (long)qq * 64 + hc * 16 + h5 * 8);

    f32x16 o0 = {}, o1 = {};                    // O^T[h][q]
    float mrun = -1e30f, lrun = 0.f;
    const int nkt = (g >> 1) + 1;

    for (int kt = 0; kt < nkt; ++kt) {
      const int k0 = kt << 6;
      const bool haveS1 = (k0 + 32 <= qmax);    // upper k-half below/at diagonal?

      s16x8 vf0[4], vf1[4];                     // V^T frags direct from global (L2)
#pragma unroll
      for (int c = 0; c < 4; ++c) {
        vf0[c] = *reinterpret_cast<const s16x8*>(Vb + (long)l31 * 2048 + k0 + c * 16 + h5 * 8);
        vf1[c] = *reinterpret_cast<const s16x8*>(Vb + (long)(32 + l31) * 2048 + k0 + c * 16 + h5 * 8);
      }
      s16x8 kf0[4], kf1[4];                     // K frags direct from global (L2)
#pragma unroll
      for (int hc = 0; hc < 4; ++hc)
        kf0[hc] = *reinterpret_cast<const s16x8*>(Kb + (long)(k0 + l31) * 64 + hc * 16 + h5 * 8);
      if (haveS1)
#pragma unroll
        for (int hc = 0; hc < 4; ++hc)
          kf1[hc] = *reinterpret_cast<const s16x8*>(Kb + (long)(k0 + 32 + l31) * 64 + hc * 16 + h5 * 8);

      // S^T = K . Q^T  (D-layout: col=q=lane&31, row=k-local)
      f32x16 s0v = {}, s1v = {};
#pragma unroll
      for (int hc = 0; hc < 4; ++hc)
        s0v = __builtin_amdgcn_mfma_f32_32x32x16_bf16(kf0[hc], qf[hc], s0v, 0, 0, 0);
      if (haveS1)
#pragma unroll
        for (int hc = 0; hc < 4; ++hc)
          s1v = __builtin_amdgcn_mfma_f32_32x32x16_bf16(kf1[hc], qf[hc], s1v, 0, 0, 0);

      if (kt == nkt - 1) {                      // diagonal tile: mask k > q
#pragma unroll
        for (int r = 0; r < 16; ++r) {
          int kA = k0 + (r & 3) + 8 * (r >> 2) + 4 * h5;
          if (kA > qq) s0v[r] = -1e30f;
          if (kA + 32 > qq) s1v[r] = -1e30f;
        }
      }

      float pmax = s0v[0];
#pragma unroll
      for (int r = 1; r < 16; ++r) pmax = fmaxf(pmax, s0v[r]);
      if (haveS1)
#pragma unroll
        for (int r = 0; r < 16; ++r) pmax = fmaxf(pmax, s1v[r]);
      pmax = fmaxf(pmax, __shfl_xor(pmax, 32));

      if (__any(pmax > mrun + 11.5f)) {         // defer-max (T13, log2 units)
        float mnew = fmaxf(mrun, pmax);
        float scl = __builtin_exp2f(mrun - mnew);
        lrun *= scl;
#pragma unroll
        for (int r = 0; r < 16; ++r) { o0[r] *= scl; o1[r] *= scl; }
        mrun = mnew;
      }
      float rs = 0.f;
#pragma unroll
      for (int r = 0; r < 16; ++r) { s0v[r] = __builtin_exp2f(s0v[r] - mrun); rs += s0v[r]; }
      if (haveS1)
#pragma unroll
        for (int r = 0; r < 16; ++r) { s1v[r] = __builtin_exp2f(s1v[r] - mrun); rs += s1v[r]; }
      rs += __shfl_xor(rs, 32);
      lrun += rs;

      // P -> bf16 B-frags via cvt_pk + permlane32_swap (T12)
      unsigned PK0[8], PK1[8];
#pragma unroll
      for (int m2 = 0; m2 < 8; ++m2) PK0[m2] = cvtpk(s0v[2 * m2], s0v[2 * m2 + 1]);
      if (haveS1)
#pragma unroll
        for (int m2 = 0; m2 < 8; ++m2) PK1[m2] = cvtpk(s1v[2 * m2], s1v[2 * m2 + 1]);

#pragma unroll
      for (int c = 0; c < 4; ++c) {
        if (c >= 2 && !haveS1) break;           // uniform: skip zero k-half
        int base = (c & 1) * 4;
        unsigned x0 = (c >> 1) ? PK1[base + 0] : PK0[base + 0];
        unsigned y0 = (c >> 1) ? PK1[base + 2] : PK0[base + 2];
        unsigned x1 = (c >> 1) ? PK1[base + 1] : PK0[base + 1];
        unsigned y1 = (c >> 1) ? PK1[base + 3] : PK0[base + 3];
        pswap(x0, y0);
        pswap(x1, y1);
        union { s32x4 i; s16x8 h; } u;
        u.i = s32x4{(int)x0, (int)x1, (int)y0, (int)y1};
        o0 = __builtin_amdgcn_mfma_f32_32x32x16_bf16(vf0[c], u.h, o0, 0, 0, 0);
        o1 = __builtin_amdgcn_mfma_f32_32x32x16_bf16(vf1[c], u.h, o1, 0, 0, 0);
      }
    }

    // epilogue: normalize, transpose O^T->O via wave-private LDS, coalesced store
    float inv = 1.0f / lrun;
#pragma unroll
    for (int hb = 0; hb < 2; ++hb) {
#pragma unroll
      for (int rp = 0; rp < 8; ++rp) {
        float vlo = (hb ? o1[2 * rp] : o0[2 * rp]) * inv;
        float vhi = (hb ? o1[2 * rp + 1] : o0[2 * rp + 1]) * inv;
        unsigned d = cvtpk(vlo, vhi);
        int col = 16 * hb + 4 * (rp >> 1) + 2 * h5 + (rp & 1);
        Zl[wv][l31 * 33 + col] = d;
      }
    }
    asm volatile("s_waitcnt lgkmcnt(0)" ::: "memory");   // wave-local LDS ordering
    const int qr = lane >> 1, cbs = (lane & 1) * 16;
    const long zb = ((long)(b * 2048 + r0 + qr)) * 512 + n * 32;   // dword index
#pragma unroll
    for (int c2 = 0; c2 < 4; ++c2) {
      u32x4 w4;
#pragma unroll
      for (int i2 = 0; i2 < 4; ++i2) w4[i2] = Zl[wv][qr * 33 + cbs + 4 * c2 + i2];
      *reinterpret_cast<u32x4*>(Zd + zb + cbs + 4 * c2) = w4;
    }
  }
}

// ---------------- launcher ----------------
extern "C" void kernel_launch(void* const* d_in, const int* in_sizes, int n_in,
                              void* d_out, int out_size, void* d_ws, size_t ws_size,
                              hipStream_t stream) {
  const float* x  = (const float*)d_in[0];
  const float* wq = (const float*)d_in[1];
  const float* wk = (const float*)d_in[2];
  const float* wv = (const float*)d_in[3];
  const float* wo = (const float*)d_in[4];
  const float* bq = (const float*)d_in[5];
  const float* bk = (const float*)d_in[6];
  const float* bv = (const float*)d_in[7];
  const float* bo = (const float*)d_in[8];
  char* ws = (char*)d_ws;
  unsigned short* xb  = (unsigned short*)(ws);                  // 8 MiB  [4096][1024]
  unsigned short* Wt  = (unsigned short*)(ws + (8  << 20));     // 6 MiB  [3][16][64][1024]
  unsigned short* Wot = (unsigned short*)(ws + (14 << 20));     // 2 MiB  [1024][1024]
  unsigned short* Qw  = (unsigned short*)(ws + (16 << 20));     // 8 MiB  [2][16][2048][64]
  unsigned short* Kw  = (unsigned short*)(ws + (24 << 20));     // 8 MiB  [2][16][2048][64]
  unsigned short* Vw  = (unsigned short*)(ws + (32 << 20));     // 8 MiB  [2][16][64][2048] (V^T)
  unsigned short* Zw  = (unsigned short*)(ws + (40 << 20));     // 8 MiB  [4096][1024]
  float* out = (float*)d_out;

  k_prep<<<20480, 256, 0, stream>>>(x, wq, wk, wv, wo, xb, Wt, Wot);
  k_gemm<0><<<dim3(24, 32), 256, 0, stream>>>(xb, Wt, bq, bk, bv, nullptr, Qw, Kw, Vw, nullptr);
  k_attn   <<<512, 128, 0, stream>>>(Qw, Kw, Vw, Zw);
  k_gemm<1><<<dim3(8, 32),  256, 0, stream>>>(Zw, Wot, nullptr, nullptr, nullptr, bo,
                                              nullptr, nullptr, nullptr, out);
}